// Round 6
// baseline (723.058 us; speedup 1.0000x reference)
//
#include <hip/hip_runtime.h>
#include <hip/hip_bf16.h>

// GraphSageLayer on MI355X. B=4, N=4096, D_IN=REP=D_OUT=128.
// proj (nodes->3 reps, bf16) -> agg (adj @ in_rep, adj^T @ out_rep) -> final (concat @ W_upd^T, tanh).
//
// R6: agg with NO LDS and NO barriers. R2/R4/R5 evidence: the per-epoch
// vmcnt(0)+s_barrier drain caps effective HBM at 1.4-2.0 TB/s regardless of
// prefetch depth (m97-plateau, but 5x cost at 16 MFMA/barrier). Fix by
// operand-role choice: A = rep_t[v][j] (m=v, 16B contiguous bf16 frags),
// B = adj (n=i):
//   !TC: B[k=j][n=i]=adj[i][j] -> 32B contiguous fp32 per lane, full lines.
//   TC:  B[k=j][n=i]=adj[j][i] -> 8 stride-16KB dwords per frag; 2 n-frags
//        (32 i) consume each 128B line exactly once -> no byte inflation.
// D[m=v][n=i] -> 8B agg[i][v0..3] stores. Waves drift freely; 2-step named
// register prefetch (R5 no-spill pattern); 1024 blocks = 4/CU, 16 waves/CU.

typedef __attribute__((ext_vector_type(8))) short short8;
typedef __attribute__((ext_vector_type(4))) float f32x4;
typedef __attribute__((ext_vector_type(4))) unsigned short u16x4;

#define MFMA(a, b, c) __builtin_amdgcn_mfma_f32_16x16x32_bf16(a, b, c, 0, 0, 0)

__device__ __forceinline__ unsigned short f2bf(float x) {
  union { float f; unsigned u; } v; v.f = x;
  unsigned r = v.u + 0x7FFFu + ((v.u >> 16) & 1u);   // RNE to bf16
  return (unsigned short)(r >> 16);
}

__device__ __forceinline__ short8 pack8(float4 a, float4 b) {
  short8 v;
  v[0] = (short)f2bf(a.x); v[1] = (short)f2bf(a.y); v[2] = (short)f2bf(a.z); v[3] = (short)f2bf(a.w);
  v[4] = (short)f2bf(b.x); v[5] = (short)f2bf(b.y); v[6] = (short)f2bf(b.z); v[7] = (short)f2bf(b.w);
  return v;
}

__device__ __forceinline__ short8 pack8f(const float* s) {
  short8 v;
#pragma unroll
  for (int t = 0; t < 8; ++t) v[t] = (short)f2bf(s[t]);
  return v;
}

// ---------------------------------------------------------------------------
// Kernel 1: projections (all three). rep = elu(nodes @ W^T + b).
// grid = 256 blocks x 256 thr; block = 64 nodes; nodes read once.
// ---------------------------------------------------------------------------
__global__ __launch_bounds__(256) void proj_kernel(
    const float* __restrict__ nodes,   // [16384][128]
    const float* __restrict__ W_in, const float* __restrict__ b_in,
    const float* __restrict__ W_out, const float* __restrict__ b_out,
    const float* __restrict__ W_node, const float* __restrict__ b_node,
    unsigned short* __restrict__ in_rep_t,   // [4][128][4096]
    unsigned short* __restrict__ out_rep_t,  // [4][128][4096]
    unsigned short* __restrict__ node_rep)   // [4][4096][128]
{
  const int tid  = threadIdx.x;
  const int lane = tid & 63;
  const int w    = tid >> 6;
  const int q    = lane >> 4;
  const int r15  = lane & 15;
  const int m0   = blockIdx.x * 64 + w * 16;

  short8 a[4];
#pragma unroll
  for (int ks = 0; ks < 4; ++ks) {
    const float* p = nodes + (size_t)(m0 + r15) * 128 + ks * 32 + q * 8;
    a[ks] = pack8(*(const float4*)p, *(const float4*)(p + 4));
  }

  const float* Ws[3]     = { W_in, W_out, W_node };
  const float* biases[3] = { b_in, b_out, b_node };

  for (int wsel = 0; wsel < 3; ++wsel) {
    const float* W    = Ws[wsel];
    const float* bias = biases[wsel];

    f32x4 acc[8];
#pragma unroll
    for (int nt = 0; nt < 8; ++nt) acc[nt] = (f32x4)0.0f;

#pragma unroll
    for (int ks = 0; ks < 4; ++ks)
#pragma unroll
      for (int nt = 0; nt < 8; ++nt) {
        const float* p = W + (size_t)(nt * 16 + r15) * 128 + ks * 32 + q * 8;
        short8 bv = pack8(*(const float4*)p, *(const float4*)(p + 4));
        acc[nt] = MFMA(a[ks], bv, acc[nt]);
      }

#pragma unroll
    for (int nt = 0; nt < 8; ++nt) {
      const int rcol = nt * 16 + r15;
      const float bv = bias[rcol];
      const int g0 = m0 + q * 4;
      float x[4];
#pragma unroll
      for (int c = 0; c < 4; ++c) {
        float t = acc[nt][c] + bv;
        x[c] = (t > 0.f) ? t : (expf(t) - 1.f);   // ELU
      }
      if (wsel < 2) {
        unsigned short* rep = (wsel == 0) ? in_rep_t : out_rep_t;
        const int b = g0 >> 12, j = g0 & 4095;
        u16x4 o;
#pragma unroll
        for (int c = 0; c < 4; ++c) o[c] = f2bf(x[c]);
        *(u16x4*)&rep[((size_t)b << 19) + (size_t)rcol * 4096 + j] = o;
      } else {
#pragma unroll
        for (int c = 0; c < 4; ++c)
          node_rep[(size_t)(g0 + c) * 128 + rcol] = f2bf(x[c]);
      }
    }
  }
}

// ---------------------------------------------------------------------------
// Kernel 2: aggregations, no LDS, no barriers. grid = 1024 x 256:
//   id&1==0: in_agg[i,v]  = sum_j adj[b][i][j] * in_rep[j][v]
//   id&1==1: out_agg[i,v] = sum_j adj[b][j][i] * out_rep[j][v]   (TC)
// Block = 4 waves; wave = 32 v (w*32, 2 m-frags) x 32 i (2 n-frags);
// block covers 128 v x 32 i; 128 k-steps of 32 j. A = rep_t (global bf16),
// B = adj (global fp32, packed to bf16 in VALU). 2-step named-reg prefetch.
// ---------------------------------------------------------------------------
template <bool TC>
__device__ __forceinline__ void agg_half(
    const float* __restrict__ adjb,         // adj + b*2^24
    const unsigned short* __restrict__ rep, // rep_t + b*2^19
    unsigned short* __restrict__ agg,       // agg + b*2^19
    int i0)
{
  const int tid  = threadIdx.x;
  const int lane = tid & 63;
  const int w    = tid >> 6;
  const int q    = lane >> 4;
  const int r15  = lane & 15;

  // A (rep_t): v = w*32 + mt*16 + r15, k-offset q*8
  const unsigned short* arow[2];
#pragma unroll
  for (int mt = 0; mt < 2; ++mt)
    arow[mt] = rep + (size_t)(w * 32 + mt * 16 + r15) * 4096 + q * 8;

  // B (adj): n = i = i0 + nt*16 + r15, k = e*32 + q*8 + t
  const float* brow[2];
#pragma unroll
  for (int nt = 0; nt < 2; ++nt) {
    if (!TC) brow[nt] = adjb + (size_t)(i0 + nt * 16 + r15) * 4096 + q * 8;
    else     brow[nt] = adjb + (size_t)(q * 8) * 4096 + i0 + nt * 16 + r15;
  }

  f32x4 acc[2][2];
#pragma unroll
  for (int mt = 0; mt < 2; ++mt)
#pragma unroll
    for (int nt = 0; nt < 2; ++nt) acc[mt][nt] = (f32x4)0.0f;

  // 2-step-deep prefetch, named register sets (no dynamic indexing).
  short8 a0[2], a1[2];
  float  b0[2][8], b1[2][8];

  auto loadA = [&](int e, short8* d) {
#pragma unroll
    for (int mt = 0; mt < 2; ++mt) d[mt] = *(const short8*)(arow[mt] + e * 32);
  };
  auto loadB = [&](int e, float (*d)[8]) {
#pragma unroll
    for (int nt = 0; nt < 2; ++nt) {
      if (!TC) {
        const float* p = brow[nt] + e * 32;
        float4 x = *(const float4*)p, y = *(const float4*)(p + 4);
        d[nt][0] = x.x; d[nt][1] = x.y; d[nt][2] = x.z; d[nt][3] = x.w;
        d[nt][4] = y.x; d[nt][5] = y.y; d[nt][6] = y.z; d[nt][7] = y.w;
      } else {
        const float* p = brow[nt] + (size_t)e * 32 * 4096;
#pragma unroll
        for (int t = 0; t < 8; ++t) d[nt][t] = p[(size_t)t * 4096];
      }
    }
  };
  auto mfstep = [&](const short8* a, float (*braw)[8]) {
    short8 bp[2];
#pragma unroll
    for (int nt = 0; nt < 2; ++nt) bp[nt] = pack8f(braw[nt]);
#pragma unroll
    for (int mt = 0; mt < 2; ++mt)
#pragma unroll
      for (int nt = 0; nt < 2; ++nt)
        acc[mt][nt] = MFMA(a[mt], bp[nt], acc[mt][nt]);
  };

  // prologue: steps 0 and 1 in flight
  loadA(0, a0); loadB(0, b0);
  loadA(1, a1); loadB(1, b1);

  for (int e = 0; e < 128; e += 2) {
    mfstep(a0, b0);
    if (e < 126) { loadA(e + 2, a0); loadB(e + 2, b0); }
    mfstep(a1, b1);
    if (e < 126) { loadA(e + 3, a1); loadB(e + 3, b1); }
  }

  // epilogue: D[m=v][n=i]: lane holds 4 consecutive v at fixed i -> 8B store
#pragma unroll
  for (int mt = 0; mt < 2; ++mt) {
    const int v0 = w * 32 + mt * 16 + q * 4;
#pragma unroll
    for (int nt = 0; nt < 2; ++nt) {
      const int i = i0 + nt * 16 + r15;
      u16x4 o;
#pragma unroll
      for (int c = 0; c < 4; ++c) o[c] = f2bf(acc[mt][nt][c]);
      *(u16x4*)&agg[(size_t)i * 128 + v0] = o;
    }
  }
}

__global__ __launch_bounds__(256, 4) void agg_kernel(
    const float* __restrict__ adj,
    const unsigned short* __restrict__ in_rep_t,
    const unsigned short* __restrict__ out_rep_t,
    unsigned short* __restrict__ in_agg,
    unsigned short* __restrict__ out_agg)
{
  const int id   = blockIdx.x;     // 1024
  const int pass = id & 1;
  const int t    = id >> 1;        // [0,512)
  const int b    = t >> 7;         // 4 batches x 128 i-tiles
  const int i0   = (t & 127) * 32;
  const float* adjb = adj + ((size_t)b << 24);
  if (pass)
    agg_half<true >(adjb, out_rep_t + ((size_t)b << 19), out_agg + ((size_t)b << 19), i0);
  else
    agg_half<false>(adjb, in_rep_t  + ((size_t)b << 19), in_agg  + ((size_t)b << 19), i0);
}

// ---------------------------------------------------------------------------
// Kernel 3: out[n,o] = tanh(sum_k upd[n,k] * W_upd[o,k] + b_upd[o]),
// upd = concat(in_agg, node_rep, out_agg). grid=512 (n-tile 32).
// ---------------------------------------------------------------------------
__global__ __launch_bounds__(256) void final_kernel(
    const unsigned short* __restrict__ in_agg,    // [16384][128]
    const unsigned short* __restrict__ node_rep,  // [16384][128]
    const unsigned short* __restrict__ out_agg,   // [16384][128]
    const float* __restrict__ W_upd,              // [128][384]
    const float* __restrict__ b_upd,              // [128]
    float* __restrict__ out)                      // [16384][128]
{
  const int tid  = threadIdx.x;
  const int lane = tid & 63;
  const int w    = tid >> 6;
  const int q    = lane >> 4;
  const int r15  = lane & 15;
  const int n0   = blockIdx.x * 32;

  const unsigned short* srcs[3] = { in_agg, node_rep, out_agg };

  f32x4 acc[2][2];
#pragma unroll
  for (int mt = 0; mt < 2; ++mt)
#pragma unroll
    for (int nt = 0; nt < 2; ++nt) acc[mt][nt] = (f32x4)0.0f;

#pragma unroll
  for (int ks = 0; ks < 12; ++ks) {
    const unsigned short* src = srcs[ks >> 2];
    const int col0 = (ks & 3) * 32 + q * 8;
    short8 a[2];
#pragma unroll
    for (int mt = 0; mt < 2; ++mt) {
      const float* p = W_upd + (size_t)(w * 32 + mt * 16 + r15) * 384 + ks * 32 + q * 8;
      a[mt] = pack8(*(const float4*)p, *(const float4*)(p + 4));
    }
#pragma unroll
    for (int nt = 0; nt < 2; ++nt) {
      const int g = n0 + nt * 16 + r15;
      short8 bv = *(const short8*)&src[(size_t)g * 128 + col0];
      acc[0][nt] = MFMA(a[0], bv, acc[0][nt]);
      acc[1][nt] = MFMA(a[1], bv, acc[1][nt]);
    }
  }

#pragma unroll
  for (int mt = 0; mt < 2; ++mt) {
    const int o0 = w * 32 + mt * 16 + q * 4;
#pragma unroll
    for (int nt = 0; nt < 2; ++nt) {
      const int g = n0 + nt * 16 + r15;
      f32x4 ov;
#pragma unroll
      for (int c = 0; c < 4; ++c) ov[c] = tanhf(acc[mt][nt][c] + b_upd[o0 + c]);
      *(f32x4*)&out[(size_t)g * 128 + o0] = ov;
    }
  }
}

// ---------------------------------------------------------------------------
extern "C" void kernel_launch(void* const* d_in, const int* in_sizes, int n_in,
                              void* d_out, int out_size, void* d_ws, size_t ws_size,
                              hipStream_t stream) {
  (void)in_sizes; (void)n_in; (void)out_size; (void)ws_size;
  const float* nodes  = (const float*)d_in[0];
  const float* adj    = (const float*)d_in[1];
  const float* W_in   = (const float*)d_in[2];
  const float* b_in   = (const float*)d_in[3];
  const float* W_out  = (const float*)d_in[4];
  const float* b_out  = (const float*)d_in[5];
  const float* W_node = (const float*)d_in[6];
  const float* b_node = (const float*)d_in[7];
  const float* W_upd  = (const float*)d_in[8];
  const float* b_upd  = (const float*)d_in[9];
  float* out = (float*)d_out;

  unsigned short* ws = (unsigned short*)d_ws;
  const size_t SZ = (size_t)4 * 128 * 4096;
  unsigned short* in_rep_t  = ws;
  unsigned short* out_rep_t = ws + SZ;
  unsigned short* node_rep  = ws + 2 * SZ;
  unsigned short* in_agg    = ws + 3 * SZ;
  unsigned short* out_agg   = ws + 4 * SZ;

  proj_kernel<<<256, 256, 0, stream>>>(
      nodes, W_in, b_in, W_out, b_out, W_node, b_node,
      in_rep_t, out_rep_t, node_rep);
  agg_kernel<<<1024, 256, 0, stream>>>(adj, in_rep_t, out_rep_t, in_agg, out_agg);
  final_kernel<<<512, 256, 0, stream>>>(in_agg, node_rep, out_agg, W_upd, b_upd, out);
}